// Round 4
// baseline (412.264 us; speedup 1.0000x reference)
//
#include <hip/hip_runtime.h>

#define D 128
#define BKT_SHIFT 9
#define BKT_SIZE 512
#define P1_EPB 4096
#define SW_LDU 68   // uints per W row in LDS (136 ushorts = 128 + 8 pad)

typedef __attribute__((ext_vector_type(8))) short bf16x8;
typedef __attribute__((ext_vector_type(4))) float f32x4;

__device__ inline unsigned int pack2bf(float a, float b) {
    unsigned int ua = __float_as_uint(a);
    unsigned int ub = __float_as_uint(b);
    ua = (ua + 0x7fffu + ((ua >> 16) & 1u)) >> 16;   // RNE
    ub = (ub + 0x7fffu + ((ub >> 16) & 1u)) >> 16;
    return ua | (ub << 16);
}
__device__ inline unsigned short pack1bf(float a) {
    unsigned int ua = __float_as_uint(a);
    return (unsigned short)((ua + 0x7fffu + ((ua >> 16) & 1u)) >> 16);
}

// ================= CSR build: histogram + scan =================

__global__ __launch_bounds__(256) void hist_kernel(
    const int* __restrict__ edst, int* __restrict__ cnt, int n_edges)
{
    int gid = blockIdx.x * 256 + threadIdx.x;
    if (gid < n_edges) atomicAdd(&cnt[edst[gid]], 1);
}

__global__ __launch_bounds__(256) void scanA_kernel(
    const int* __restrict__ cnt, int* __restrict__ localoff,
    int* __restrict__ blocksums, int n)
{
    __shared__ int s[256];
    const int t = threadIdx.x;
    const int base = blockIdx.x * 1024 + t * 4;
    int v[4]; int sum = 0;
    #pragma unroll
    for (int i = 0; i < 4; i++) {
        int idx = base + i;
        v[i] = (idx < n) ? cnt[idx] : 0;
        sum += v[i];
    }
    s[t] = sum;
    __syncthreads();
    #pragma unroll
    for (int off = 1; off < 256; off <<= 1) {
        int x = (t >= off) ? s[t - off] : 0;
        __syncthreads();
        s[t] += x;
        __syncthreads();
    }
    int excl = s[t] - sum;
    int run = 0;
    #pragma unroll
    for (int i = 0; i < 4; i++) {
        int idx = base + i;
        if (idx < n) localoff[idx] = excl + run;
        run += v[i];
    }
    if (t == 255) blocksums[blockIdx.x] = s[255];
}

__global__ __launch_bounds__(256) void scanB_kernel(
    const int* __restrict__ blocksums, int* __restrict__ blockoffs, int nb)
{
    __shared__ int s[256];
    const int t = threadIdx.x;
    int v = (t < nb) ? blocksums[t] : 0;
    s[t] = v;
    __syncthreads();
    #pragma unroll
    for (int off = 1; off < 256; off <<= 1) {
        int x = (t >= off) ? s[t - off] : 0;
        __syncthreads();
        s[t] += x;
        __syncthreads();
    }
    if (t < nb) blockoffs[t] = s[t] - v;
}

// outoffs[g] = localoff[g] + blockoffs[g/1024]; optional cursor copy.
// outoffs may alias localoff (same-index read-then-write).
__global__ __launch_bounds__(256) void scanC_kernel(
    const int* __restrict__ localoff, const int* __restrict__ blockoffs,
    int* __restrict__ outoffs, int* __restrict__ cursor, int n)
{
    int gid = blockIdx.x * 256 + threadIdx.x;
    if (gid >= n) return;
    int v = localoff[gid] + blockoffs[blockIdx.x >> 2];
    outoffs[gid] = v;
    if (cursor) cursor[gid] = v;
}

// ================= bucketed placement =================

__global__ __launch_bounds__(256) void init_bucket_kernel(
    const int* __restrict__ offs, int* __restrict__ bucketCur, int nbk)
{
    int t = blockIdx.x * 256 + threadIdx.x;
    if (t < nbk) bucketCur[t] = offs[t << BKT_SHIFT];
}

// P1: partition edges into 512-node buckets; chunked mostly-coalesced writes.
__global__ __launch_bounds__(256) void p1_partition_kernel(
    const int* __restrict__ esrc, const int* __restrict__ edst,
    int* __restrict__ bucketCur, uint2* __restrict__ pairs, int n_edges)
{
    __shared__ int hcnt[256];
    __shared__ int hbase[256];
    const int tid = threadIdx.x;
    const int base = blockIdx.x * P1_EPB;
    hcnt[tid] = 0;
    __syncthreads();
    int rs[16], rd[16];
    #pragma unroll
    for (int k = 0; k < 16; k++) {
        int e = base + k * 256 + tid;
        if (e < n_edges) {
            rs[k] = esrc[e];
            rd[k] = edst[e];
            atomicAdd(&hcnt[rd[k] >> BKT_SHIFT], 1);
        } else rd[k] = -1;
    }
    __syncthreads();
    int cval = hcnt[tid];
    if (cval > 0) hbase[tid] = atomicAdd(&bucketCur[tid], cval);
    hcnt[tid] = 0;   // reuse as local cursor
    __syncthreads();
    #pragma unroll
    for (int k = 0; k < 16; k++) {
        if (rd[k] >= 0) {
            int bk = rd[k] >> BKT_SHIFT;
            int loc = atomicAdd(&hcnt[bk], 1);
            pairs[hbase[bk] + loc] = make_uint2((unsigned)rs[k], (unsigned)rd[k]);
        }
    }
}

// P2: within-bucket placement with LDS cursors; writes stay in a ~32KB window.
__global__ __launch_bounds__(256) void p2_place_kernel(
    const uint2* __restrict__ pairs, const int* __restrict__ offs,
    int* __restrict__ sorted_src, int n_nodes, int n_edges, int nbk)
{
    __shared__ int lcur[BKT_SIZE];
    const int tid = threadIdx.x;
    const int bkt = blockIdx.x;
    const int nbase = bkt << BKT_SHIFT;
    for (int i = tid; i < BKT_SIZE; i += 256) {
        int nd = nbase + i;
        lcur[i] = (nd < n_nodes) ? offs[nd] : 0;
    }
    __syncthreads();
    const int pstart = offs[nbase];
    const int pend = (bkt == nbk - 1) ? n_edges : offs[nbase + BKT_SIZE];
    for (int j = pstart + tid; j < pend; j += 256) {
        uint2 p = pairs[j];
        int pos = atomicAdd(&lcur[p.y - (unsigned)nbase], 1);
        sorted_src[pos] = (int)p.x;
    }
}

// ================= GEMM first: z = bf16(h @ W^T) =================
__global__ __launch_bounds__(256) void gemm_z_kernel(
    const float* __restrict__ h, const float* __restrict__ W,
    unsigned short* __restrict__ z, int n_nodes)
{
    __shared__ unsigned int sW[128 * SW_LDU];
    const int tid = threadIdx.x;
    for (int i = tid; i < 4096; i += 256) {
        float4 w = ((const float4*)W)[i];
        int row = i >> 5, c4 = i & 31;
        unsigned int* dst = &sW[row * SW_LDU + c4 * 2];
        dst[0] = pack2bf(w.x, w.y);
        dst[1] = pack2bf(w.z, w.w);
    }
    __syncthreads();

    const int wave = tid >> 6;
    const int lane = tid & 63;
    const int m = lane & 15;
    const int q = lane >> 4;
    const int r0 = blockIdx.x * 64 + wave * 16;
    const int arow = r0 + m;
    const bool rvalid = arow < n_nodes;

    bf16x8 afrag[4];
    #pragma unroll
    for (int ks = 0; ks < 4; ks++) {
        float4 x = make_float4(0.f, 0.f, 0.f, 0.f), y = x;
        if (rvalid) {
            const float4* p = (const float4*)(h + (size_t)arow * D + ks * 32 + q * 8);
            x = p[0]; y = p[1];
        }
        union { unsigned int u[4]; bf16x8 v; } cvt;
        cvt.u[0] = pack2bf(x.x, x.y);
        cvt.u[1] = pack2bf(x.z, x.w);
        cvt.u[2] = pack2bf(y.x, y.y);
        cvt.u[3] = pack2bf(y.z, y.w);
        afrag[ks] = cvt.v;
    }

    f32x4 acc[8];
    #pragma unroll
    for (int ct = 0; ct < 8; ct++) acc[ct] = (f32x4){0.f, 0.f, 0.f, 0.f};

    #pragma unroll
    for (int ct = 0; ct < 8; ct++) {
        #pragma unroll
        for (int ks = 0; ks < 4; ks++) {
            const unsigned int* p = &sW[(ct * 16 + m) * SW_LDU + ks * 16 + q * 4];
            union { uint4 u; bf16x8 v; } bu;
            bu.u = *(const uint4*)p;
            acc[ct] = __builtin_amdgcn_mfma_f32_16x16x32_bf16(afrag[ks], bu.v, acc[ct], 0, 0, 0);
        }
    }

    #pragma unroll
    for (int ct = 0; ct < 8; ct++) {
        int col = ct * 16 + m;
        #pragma unroll
        for (int i = 0; i < 4; i++) {
            int r = r0 + q * 4 + i;
            if (r < n_nodes) z[(size_t)r * D + col] = pack1bf(acc[ct][i]);
        }
    }
}

// ================= column-split gather + bias + relu =================
// chunk c = blockIdx&7 -> 16 cols; same-chunk blocks share an XCD (blk%8
// round-robin heuristic) so the 3.2MB z-column slice stays L2-resident.
__global__ __launch_bounds__(256) void gather_col_kernel(
    const unsigned short* __restrict__ z, const int* __restrict__ offs,
    const int* __restrict__ cnt, const int* __restrict__ sorted_src,
    const float* __restrict__ b, float* __restrict__ out, int n_nodes)
{
    const int tid = threadIdx.x;
    const int c = blockIdx.x & 7;
    const int g = blockIdx.x >> 3;
    const int node = g * 32 + (tid >> 3);
    const int l8 = tid & 7;
    if (node >= n_nodes) return;
    const int col0 = c * 16 + l8 * 2;
    const int start = offs[node];
    const int end = start + cnt[node];
    const unsigned short* zc = z + col0;
    float ax = 0.f, ay = 0.f;
    int e = start;
    for (; e + 4 <= end; e += 4) {
        int s0 = sorted_src[e + 0];
        int s1 = sorted_src[e + 1];
        int s2 = sorted_src[e + 2];
        int s3 = sorted_src[e + 3];
        unsigned int u0 = *(const unsigned int*)(zc + (size_t)s0 * D);
        unsigned int u1 = *(const unsigned int*)(zc + (size_t)s1 * D);
        unsigned int u2 = *(const unsigned int*)(zc + (size_t)s2 * D);
        unsigned int u3 = *(const unsigned int*)(zc + (size_t)s3 * D);
        ax += __uint_as_float(u0 << 16) + __uint_as_float(u1 << 16)
            + __uint_as_float(u2 << 16) + __uint_as_float(u3 << 16);
        ay += __uint_as_float(u0 & 0xffff0000u) + __uint_as_float(u1 & 0xffff0000u)
            + __uint_as_float(u2 & 0xffff0000u) + __uint_as_float(u3 & 0xffff0000u);
    }
    for (; e < end; e++) {
        unsigned int u = *(const unsigned int*)(zc + (size_t)sorted_src[e] * D);
        ax += __uint_as_float(u << 16);
        ay += __uint_as_float(u & 0xffff0000u);
    }
    float2 bb = *(const float2*)(b + col0);
    float vx = ax + bb.x, vy = ay + bb.y;
    float2* o = (float2*)(out + (size_t)node * D + col0);
    *o = make_float2(vx > 0.f ? vx : 0.f, vy > 0.f ? vy : 0.f);
}

// ================= fallback kernels (round-3 path) =================

__global__ __launch_bounds__(256) void place_kernel(
    const int* __restrict__ esrc, const int* __restrict__ edst,
    int* __restrict__ cursor, int* __restrict__ sorted_src, int n_edges)
{
    int gid = blockIdx.x * 256 + threadIdx.x;
    if (gid >= n_edges) return;
    int d = edst[gid];
    int pos = atomicAdd(&cursor[d], 1);
    sorted_src[pos] = esrc[gid];
}

__global__ __launch_bounds__(256) void gather_kernel(
    const float* __restrict__ h, const int* __restrict__ offs,
    const int* __restrict__ endp, const int* __restrict__ sorted_src,
    float* __restrict__ out, int n_nodes)
{
    const int tid = threadIdx.x;
    const int node = blockIdx.x * 8 + (tid >> 5);
    const int lane = tid & 31;
    if (node >= n_nodes) return;
    const int start = offs[node];
    const int end = endp[node];
    const float4* __restrict__ h4 = (const float4*)h;
    float4 acc = make_float4(0.f, 0.f, 0.f, 0.f);
    for (int e = start; e < end; e++) {
        float4 a = h4[(size_t)sorted_src[e] * 32 + lane];
        acc.x += a.x; acc.y += a.y; acc.z += a.z; acc.w += a.w;
    }
    ((float4*)out)[(size_t)node * 32 + lane] = acc;
}

__global__ __launch_bounds__(256) void scatter_kernel(
    const float* __restrict__ h, const int* __restrict__ esrc,
    const int* __restrict__ edst, float* __restrict__ out, int n_edges)
{
    int gid = blockIdx.x * 256 + threadIdx.x;
    int e = gid >> 5;
    int l = gid & 31;
    if (e >= n_edges) return;
    int s = esrc[e];
    int d = edst[e];
    float4 v = ((const float4*)(h + (size_t)s * D))[l];
    float* o = out + (size_t)d * D + (size_t)l * 4;
    atomicAdd(o + 0, v.x);
    atomicAdd(o + 1, v.y);
    atomicAdd(o + 2, v.z);
    atomicAdd(o + 3, v.w);
}

// in-place MFMA gemm + bias + relu (fallback epilogue)
__global__ __launch_bounds__(256) void mfma_gemm_relu_kernel(
    float* __restrict__ io, const float* __restrict__ W,
    const float* __restrict__ b, int n_nodes)
{
    __shared__ unsigned int sW[128 * SW_LDU];
    const int tid = threadIdx.x;
    for (int i = tid; i < 4096; i += 256) {
        float4 w = ((const float4*)W)[i];
        int row = i >> 5, c4 = i & 31;
        unsigned int* dst = &sW[row * SW_LDU + c4 * 2];
        dst[0] = pack2bf(w.x, w.y);
        dst[1] = pack2bf(w.z, w.w);
    }
    __syncthreads();
    const int wave = tid >> 6;
    const int lane = tid & 63;
    const int m = lane & 15;
    const int q = lane >> 4;
    const int r0 = blockIdx.x * 64 + wave * 16;
    const int arow = r0 + m;
    const bool rvalid = arow < n_nodes;
    bf16x8 afrag[4];
    #pragma unroll
    for (int ks = 0; ks < 4; ks++) {
        float4 x = make_float4(0.f, 0.f, 0.f, 0.f), y = x;
        if (rvalid) {
            const float4* p = (const float4*)(io + (size_t)arow * D + ks * 32 + q * 8);
            x = p[0]; y = p[1];
        }
        union { unsigned int u[4]; bf16x8 v; } cvt;
        cvt.u[0] = pack2bf(x.x, x.y);
        cvt.u[1] = pack2bf(x.z, x.w);
        cvt.u[2] = pack2bf(y.x, y.y);
        cvt.u[3] = pack2bf(y.z, y.w);
        afrag[ks] = cvt.v;
    }
    f32x4 acc[8];
    #pragma unroll
    for (int ct = 0; ct < 8; ct++) acc[ct] = (f32x4){0.f, 0.f, 0.f, 0.f};
    #pragma unroll
    for (int ct = 0; ct < 8; ct++) {
        #pragma unroll
        for (int ks = 0; ks < 4; ks++) {
            const unsigned int* p = &sW[(ct * 16 + m) * SW_LDU + ks * 16 + q * 4];
            union { uint4 u; bf16x8 v; } bu;
            bu.u = *(const uint4*)p;
            acc[ct] = __builtin_amdgcn_mfma_f32_16x16x32_bf16(afrag[ks], bu.v, acc[ct], 0, 0, 0);
        }
    }
    #pragma unroll
    for (int ct = 0; ct < 8; ct++) {
        int col = ct * 16 + m;
        float bias = b[col];
        #pragma unroll
        for (int i = 0; i < 4; i++) {
            int r = r0 + q * 4 + i;
            if (r < n_nodes) {
                float v = acc[ct][i] + bias;
                io[(size_t)r * D + col] = v > 0.f ? v : 0.f;
            }
        }
    }
}

extern "C" void kernel_launch(void* const* d_in, const int* in_sizes, int n_in,
                              void* d_out, int out_size, void* d_ws, size_t ws_size,
                              hipStream_t stream) {
    const float* h    = (const float*)d_in[0];
    const int*   esrc = (const int*)d_in[1];
    const int*   edst = (const int*)d_in[2];
    const float* W    = (const float*)d_in[3];
    const float* b    = (const float*)d_in[4];
    float* out = (float*)d_out;
    const int n_nodes = in_sizes[0] / D;
    const int n_edges = in_sizes[1];
    const int NB  = (n_nodes + 1023) / 1024;
    const int NBK = (n_nodes + BKT_SIZE - 1) / BKT_SIZE;

    // ---- main path: bucketed sort + gemm-first + column-split gather ----
    size_t zone_bytes = (size_t)n_edges * 8;                 // pairs
    size_t zb2 = (size_t)n_nodes * D * 2;                    // z (bf16)
    if (zb2 > zone_bytes) zone_bytes = zb2;
    size_t fixed = ((size_t)2 * n_nodes + 2 * NB + NBK + (size_t)n_edges) * 4;
    size_t zone_off = (fixed + 15) & ~(size_t)15;
    size_t need_main = zone_off + zone_bytes;

    if (ws_size >= need_main && NB <= 256 && NBK <= 256) {
        int* cnt        = (int*)d_ws;               // n_nodes (degrees)
        int* offs       = cnt + n_nodes;            // n_nodes
        int* blocksums  = offs + n_nodes;           // NB
        int* blockoffs  = blocksums + NB;           // NB
        int* bucketCur  = blockoffs + NB;           // NBK
        int* sorted_src = bucketCur + NBK;          // n_edges
        void* zone = (char*)d_ws + zone_off;
        uint2* pairs = (uint2*)zone;
        unsigned short* z = (unsigned short*)zone;  // aliases pairs (sequential use)

        hipMemsetAsync(cnt, 0, (size_t)n_nodes * sizeof(int), stream);
        hist_kernel<<<(n_edges + 255) / 256, 256, 0, stream>>>(edst, cnt, n_edges);
        scanA_kernel<<<NB, 256, 0, stream>>>(cnt, offs, blocksums, n_nodes);
        scanB_kernel<<<1, 256, 0, stream>>>(blocksums, blockoffs, NB);
        scanC_kernel<<<(n_nodes + 255) / 256, 256, 0, stream>>>(
            offs, blockoffs, offs, (int*)nullptr, n_nodes);
        init_bucket_kernel<<<1, 256, 0, stream>>>(offs, bucketCur, NBK);
        p1_partition_kernel<<<(n_edges + P1_EPB - 1) / P1_EPB, 256, 0, stream>>>(
            esrc, edst, bucketCur, pairs, n_edges);
        p2_place_kernel<<<NBK, 256, 0, stream>>>(
            pairs, offs, sorted_src, n_nodes, n_edges, NBK);
        // pairs consumed; zone reused as z
        gemm_z_kernel<<<(n_nodes + 63) / 64, 256, 0, stream>>>(h, W, z, n_nodes);
        gather_col_kernel<<<((n_nodes + 31) / 32) * 8, 256, 0, stream>>>(
            z, cnt ? offs : offs, cnt, sorted_src, b, out, n_nodes);
        return;
    }

    // ---- fallback: round-3 CSR path (fp32 gather + in-place mfma gemm) ----
    size_t csr_ints = (size_t)3 * n_nodes + 2 * NB + (size_t)n_edges;
    size_t needB = csr_ints * sizeof(int);
    if (ws_size >= needB && NB <= 256) {
        int* cnt        = (int*)d_ws;
        int* offs       = cnt + n_nodes;
        int* cursor     = offs + n_nodes;
        int* blocksums  = cursor + n_nodes;
        int* blockoffs  = blocksums + NB;
        int* sorted_src = blockoffs + NB;

        hipMemsetAsync(cnt, 0, (size_t)n_nodes * sizeof(int), stream);
        hist_kernel<<<(n_edges + 255) / 256, 256, 0, stream>>>(edst, cnt, n_edges);
        scanA_kernel<<<NB, 256, 0, stream>>>(cnt, offs, blocksums, n_nodes);
        scanB_kernel<<<1, 256, 0, stream>>>(blocksums, blockoffs, NB);
        scanC_kernel<<<(n_nodes + 255) / 256, 256, 0, stream>>>(
            offs, blockoffs, cnt, cursor, n_nodes);
        place_kernel<<<(n_edges + 255) / 256, 256, 0, stream>>>(
            esrc, edst, cursor, sorted_src, n_edges);
        gather_kernel<<<(n_nodes + 7) / 8, 256, 0, stream>>>(
            h, cnt, cursor, sorted_src, out, n_nodes);
    } else {
        hipMemsetAsync(out, 0, (size_t)n_nodes * D * sizeof(float), stream);
        long long total = (long long)n_edges * 32;
        scatter_kernel<<<(int)((total + 255) / 256), 256, 0, stream>>>(h, esrc, edst, out, n_edges);
    }
    mfma_gemm_relu_kernel<<<(n_nodes + 63) / 64, 256, 0, stream>>>(out, W, b, n_nodes);
}

// Round 5
// 334.177 us; speedup vs baseline: 1.2337x; 1.2337x over previous
//
#include <hip/hip_runtime.h>

#define D 128
#define BKT_SHIFT 9
#define BKT_SIZE 512
#define P1_EPB 4096
#define SW_LDU 68   // uints per W row in LDS (136 ushorts = 128 + 8 pad)

typedef __attribute__((ext_vector_type(8))) short bf16x8;
typedef __attribute__((ext_vector_type(4))) float f32x4;

__device__ inline unsigned int pack2bf(float a, float b) {
    unsigned int ua = __float_as_uint(a);
    unsigned int ub = __float_as_uint(b);
    ua = (ua + 0x7fffu + ((ua >> 16) & 1u)) >> 16;   // RNE
    ub = (ub + 0x7fffu + ((ub >> 16) & 1u)) >> 16;
    return ua | (ub << 16);
}
__device__ inline unsigned short pack1bf(float a) {
    unsigned int ua = __float_as_uint(a);
    return (unsigned short)((ua + 0x7fffu + ((ua >> 16) & 1u)) >> 16);
}

// ================= CSR build: histogram + scan =================

__global__ __launch_bounds__(256) void hist_kernel(
    const int* __restrict__ edst, int* __restrict__ cnt, int n_edges)
{
    int gid = blockIdx.x * 256 + threadIdx.x;
    if (gid < n_edges) atomicAdd(&cnt[edst[gid]], 1);
}

__global__ __launch_bounds__(256) void scanA_kernel(
    const int* __restrict__ cnt, int* __restrict__ localoff,
    int* __restrict__ blocksums, int n)
{
    __shared__ int s[256];
    const int t = threadIdx.x;
    const int base = blockIdx.x * 1024 + t * 4;
    int v[4]; int sum = 0;
    #pragma unroll
    for (int i = 0; i < 4; i++) {
        int idx = base + i;
        v[i] = (idx < n) ? cnt[idx] : 0;
        sum += v[i];
    }
    s[t] = sum;
    __syncthreads();
    #pragma unroll
    for (int off = 1; off < 256; off <<= 1) {
        int x = (t >= off) ? s[t - off] : 0;
        __syncthreads();
        s[t] += x;
        __syncthreads();
    }
    int excl = s[t] - sum;
    int run = 0;
    #pragma unroll
    for (int i = 0; i < 4; i++) {
        int idx = base + i;
        if (idx < n) localoff[idx] = excl + run;
        run += v[i];
    }
    if (t == 255) blocksums[blockIdx.x] = s[255];
}

__global__ __launch_bounds__(256) void scanB_kernel(
    const int* __restrict__ blocksums, int* __restrict__ blockoffs, int nb)
{
    __shared__ int s[256];
    const int t = threadIdx.x;
    int v = (t < nb) ? blocksums[t] : 0;
    s[t] = v;
    __syncthreads();
    #pragma unroll
    for (int off = 1; off < 256; off <<= 1) {
        int x = (t >= off) ? s[t - off] : 0;
        __syncthreads();
        s[t] += x;
        __syncthreads();
    }
    if (t < nb) blockoffs[t] = s[t] - v;
}

// outoffs[g] = localoff[g] + blockoffs[g/1024]; optional cursor copy and
// optional per-bucket base capture. outoffs may alias localoff.
__global__ __launch_bounds__(256) void scanC_kernel(
    const int* __restrict__ localoff, const int* __restrict__ blockoffs,
    int* __restrict__ outoffs, int* __restrict__ cursor,
    int* __restrict__ bucketCur, int n)
{
    int gid = blockIdx.x * 256 + threadIdx.x;
    if (gid >= n) return;
    int v = localoff[gid] + blockoffs[blockIdx.x >> 2];
    outoffs[gid] = v;
    if (cursor) cursor[gid] = v;
    if (bucketCur && (gid & (BKT_SIZE - 1)) == 0) bucketCur[gid >> BKT_SHIFT] = v;
}

// ================= bucketed placement =================

// P1: partition edges into 512-node buckets; chunked mostly-coalesced writes.
__global__ __launch_bounds__(256) void p1_partition_kernel(
    const int* __restrict__ esrc, const int* __restrict__ edst,
    int* __restrict__ bucketCur, uint2* __restrict__ pairs, int n_edges)
{
    __shared__ int hcnt[256];
    __shared__ int hbase[256];
    const int tid = threadIdx.x;
    const int base = blockIdx.x * P1_EPB;
    hcnt[tid] = 0;
    __syncthreads();
    int rs[16], rd[16];
    #pragma unroll
    for (int k = 0; k < 16; k++) {
        int e = base + k * 256 + tid;
        if (e < n_edges) {
            rs[k] = esrc[e];
            rd[k] = edst[e];
            atomicAdd(&hcnt[rd[k] >> BKT_SHIFT], 1);
        } else rd[k] = -1;
    }
    __syncthreads();
    int cval = hcnt[tid];
    if (cval > 0) hbase[tid] = atomicAdd(&bucketCur[tid], cval);
    hcnt[tid] = 0;   // reuse as local cursor
    __syncthreads();
    #pragma unroll
    for (int k = 0; k < 16; k++) {
        if (rd[k] >= 0) {
            int bk = rd[k] >> BKT_SHIFT;
            int loc = atomicAdd(&hcnt[bk], 1);
            pairs[hbase[bk] + loc] = make_uint2((unsigned)rs[k], (unsigned)rd[k]);
        }
    }
}

// P2: place src by bumping offs[] in place. Pairs are bucket-grouped, so
// writes from a pair-range land inside that bucket's 32KB window -> lines
// fully populated before eviction. After P2, offs[n] == row END.
__global__ __launch_bounds__(256) void p2_place_kernel(
    const uint2* __restrict__ pairs, int* __restrict__ offs,
    int* __restrict__ sorted_src, int n_edges)
{
    int gid = blockIdx.x * 256 + threadIdx.x;
    if (gid >= n_edges) return;
    uint2 p = pairs[gid];
    int pos = atomicAdd(&offs[p.y], 1);
    sorted_src[pos] = (int)p.x;
}

// ================= GEMM first: z = bf16(h @ W^T) =================
__global__ __launch_bounds__(256) void gemm_z_kernel(
    const float* __restrict__ h, const float* __restrict__ W,
    unsigned short* __restrict__ z, int n_nodes)
{
    __shared__ unsigned int sW[128 * SW_LDU];
    const int tid = threadIdx.x;
    for (int i = tid; i < 4096; i += 256) {
        float4 w = ((const float4*)W)[i];
        int row = i >> 5, c4 = i & 31;
        unsigned int* dst = &sW[row * SW_LDU + c4 * 2];
        dst[0] = pack2bf(w.x, w.y);
        dst[1] = pack2bf(w.z, w.w);
    }
    __syncthreads();

    const int wave = tid >> 6;
    const int lane = tid & 63;
    const int m = lane & 15;
    const int q = lane >> 4;
    const int r0 = blockIdx.x * 64 + wave * 16;
    const int arow = r0 + m;
    const bool rvalid = arow < n_nodes;

    bf16x8 afrag[4];
    #pragma unroll
    for (int ks = 0; ks < 4; ks++) {
        float4 x = make_float4(0.f, 0.f, 0.f, 0.f), y = x;
        if (rvalid) {
            const float4* p = (const float4*)(h + (size_t)arow * D + ks * 32 + q * 8);
            x = p[0]; y = p[1];
        }
        union { unsigned int u[4]; bf16x8 v; } cvt;
        cvt.u[0] = pack2bf(x.x, x.y);
        cvt.u[1] = pack2bf(x.z, x.w);
        cvt.u[2] = pack2bf(y.x, y.y);
        cvt.u[3] = pack2bf(y.z, y.w);
        afrag[ks] = cvt.v;
    }

    f32x4 acc[8];
    #pragma unroll
    for (int ct = 0; ct < 8; ct++) acc[ct] = (f32x4){0.f, 0.f, 0.f, 0.f};

    #pragma unroll
    for (int ct = 0; ct < 8; ct++) {
        #pragma unroll
        for (int ks = 0; ks < 4; ks++) {
            const unsigned int* p = &sW[(ct * 16 + m) * SW_LDU + ks * 16 + q * 4];
            union { uint4 u; bf16x8 v; } bu;
            bu.u = *(const uint4*)p;
            acc[ct] = __builtin_amdgcn_mfma_f32_16x16x32_bf16(afrag[ks], bu.v, acc[ct], 0, 0, 0);
        }
    }

    #pragma unroll
    for (int ct = 0; ct < 8; ct++) {
        int col = ct * 16 + m;
        #pragma unroll
        for (int i = 0; i < 4; i++) {
            int r = r0 + q * 4 + i;
            if (r < n_nodes) z[(size_t)r * D + col] = pack1bf(acc[ct][i]);
        }
    }
}

// ================= full-row gather + bias + relu =================
// 32 lanes per node (lane -> uint2 = 4 bf16 of the 256B row); 8 nodes/block.
// Each edge's 4 cache lines are read exactly once, by one 32-lane group.
// start = offs_end[node] - cnt[node]  (offs was bumped in place by P2).
__global__ __launch_bounds__(256) void gather_row_kernel(
    const unsigned short* __restrict__ z, const int* __restrict__ offs_end,
    const int* __restrict__ cnt, const int* __restrict__ sorted_src,
    const float* __restrict__ b, float* __restrict__ out, int n_nodes)
{
    const int tid = threadIdx.x;
    const int node = blockIdx.x * 8 + (tid >> 5);
    const int lane = tid & 31;
    if (node >= n_nodes) return;
    const int end = offs_end[node];
    const int start = end - cnt[node];
    const uint2* __restrict__ z2 = (const uint2*)z;   // 32 uint2 per row
    float4 acc = make_float4(0.f, 0.f, 0.f, 0.f);
    int e = start;
    for (; e + 4 <= end; e += 4) {
        int s0 = sorted_src[e + 0];
        int s1 = sorted_src[e + 1];
        int s2 = sorted_src[e + 2];
        int s3 = sorted_src[e + 3];
        uint2 v0 = z2[(size_t)s0 * 32 + lane];
        uint2 v1 = z2[(size_t)s1 * 32 + lane];
        uint2 v2 = z2[(size_t)s2 * 32 + lane];
        uint2 v3 = z2[(size_t)s3 * 32 + lane];
        acc.x += __uint_as_float(v0.x << 16) + __uint_as_float(v1.x << 16)
               + __uint_as_float(v2.x << 16) + __uint_as_float(v3.x << 16);
        acc.y += __uint_as_float(v0.x & 0xffff0000u) + __uint_as_float(v1.x & 0xffff0000u)
               + __uint_as_float(v2.x & 0xffff0000u) + __uint_as_float(v3.x & 0xffff0000u);
        acc.z += __uint_as_float(v0.y << 16) + __uint_as_float(v1.y << 16)
               + __uint_as_float(v2.y << 16) + __uint_as_float(v3.y << 16);
        acc.w += __uint_as_float(v0.y & 0xffff0000u) + __uint_as_float(v1.y & 0xffff0000u)
               + __uint_as_float(v2.y & 0xffff0000u) + __uint_as_float(v3.y & 0xffff0000u);
    }
    for (; e < end; e++) {
        uint2 v = z2[(size_t)sorted_src[e] * 32 + lane];
        acc.x += __uint_as_float(v.x << 16);
        acc.y += __uint_as_float(v.x & 0xffff0000u);
        acc.z += __uint_as_float(v.y << 16);
        acc.w += __uint_as_float(v.y & 0xffff0000u);
    }
    float4 bb = ((const float4*)b)[lane];   // cols lane*4 .. lane*4+3
    float vx = acc.x + bb.x, vy = acc.y + bb.y;
    float vz = acc.z + bb.z, vw = acc.w + bb.w;
    ((float4*)out)[(size_t)node * 32 + lane] = make_float4(
        vx > 0.f ? vx : 0.f, vy > 0.f ? vy : 0.f,
        vz > 0.f ? vz : 0.f, vw > 0.f ? vw : 0.f);
}

// ================= fallback kernels (round-3 path) =================

__global__ __launch_bounds__(256) void place_kernel(
    const int* __restrict__ esrc, const int* __restrict__ edst,
    int* __restrict__ cursor, int* __restrict__ sorted_src, int n_edges)
{
    int gid = blockIdx.x * 256 + threadIdx.x;
    if (gid >= n_edges) return;
    int d = edst[gid];
    int pos = atomicAdd(&cursor[d], 1);
    sorted_src[pos] = esrc[gid];
}

__global__ __launch_bounds__(256) void gather_kernel(
    const float* __restrict__ h, const int* __restrict__ offs,
    const int* __restrict__ endp, const int* __restrict__ sorted_src,
    float* __restrict__ out, int n_nodes)
{
    const int tid = threadIdx.x;
    const int node = blockIdx.x * 8 + (tid >> 5);
    const int lane = tid & 31;
    if (node >= n_nodes) return;
    const int start = offs[node];
    const int end = endp[node];
    const float4* __restrict__ h4 = (const float4*)h;
    float4 acc = make_float4(0.f, 0.f, 0.f, 0.f);
    for (int e = start; e < end; e++) {
        float4 a = h4[(size_t)sorted_src[e] * 32 + lane];
        acc.x += a.x; acc.y += a.y; acc.z += a.z; acc.w += a.w;
    }
    ((float4*)out)[(size_t)node * 32 + lane] = acc;
}

__global__ __launch_bounds__(256) void scatter_kernel(
    const float* __restrict__ h, const int* __restrict__ esrc,
    const int* __restrict__ edst, float* __restrict__ out, int n_edges)
{
    int gid = blockIdx.x * 256 + threadIdx.x;
    int e = gid >> 5;
    int l = gid & 31;
    if (e >= n_edges) return;
    int s = esrc[e];
    int d = edst[e];
    float4 v = ((const float4*)(h + (size_t)s * D))[l];
    float* o = out + (size_t)d * D + (size_t)l * 4;
    atomicAdd(o + 0, v.x);
    atomicAdd(o + 1, v.y);
    atomicAdd(o + 2, v.z);
    atomicAdd(o + 3, v.w);
}

// in-place MFMA gemm + bias + relu (fallback epilogue)
__global__ __launch_bounds__(256) void mfma_gemm_relu_kernel(
    float* __restrict__ io, const float* __restrict__ W,
    const float* __restrict__ b, int n_nodes)
{
    __shared__ unsigned int sW[128 * SW_LDU];
    const int tid = threadIdx.x;
    for (int i = tid; i < 4096; i += 256) {
        float4 w = ((const float4*)W)[i];
        int row = i >> 5, c4 = i & 31;
        unsigned int* dst = &sW[row * SW_LDU + c4 * 2];
        dst[0] = pack2bf(w.x, w.y);
        dst[1] = pack2bf(w.z, w.w);
    }
    __syncthreads();
    const int wave = tid >> 6;
    const int lane = tid & 63;
    const int m = lane & 15;
    const int q = lane >> 4;
    const int r0 = blockIdx.x * 64 + wave * 16;
    const int arow = r0 + m;
    const bool rvalid = arow < n_nodes;
    bf16x8 afrag[4];
    #pragma unroll
    for (int ks = 0; ks < 4; ks++) {
        float4 x = make_float4(0.f, 0.f, 0.f, 0.f), y = x;
        if (rvalid) {
            const float4* p = (const float4*)(io + (size_t)arow * D + ks * 32 + q * 8);
            x = p[0]; y = p[1];
        }
        union { unsigned int u[4]; bf16x8 v; } cvt;
        cvt.u[0] = pack2bf(x.x, x.y);
        cvt.u[1] = pack2bf(x.z, x.w);
        cvt.u[2] = pack2bf(y.x, y.y);
        cvt.u[3] = pack2bf(y.z, y.w);
        afrag[ks] = cvt.v;
    }
    f32x4 acc[8];
    #pragma unroll
    for (int ct = 0; ct < 8; ct++) acc[ct] = (f32x4){0.f, 0.f, 0.f, 0.f};
    #pragma unroll
    for (int ct = 0; ct < 8; ct++) {
        #pragma unroll
        for (int ks = 0; ks < 4; ks++) {
            const unsigned int* p = &sW[(ct * 16 + m) * SW_LDU + ks * 16 + q * 4];
            union { uint4 u; bf16x8 v; } bu;
            bu.u = *(const uint4*)p;
            acc[ct] = __builtin_amdgcn_mfma_f32_16x16x32_bf16(afrag[ks], bu.v, acc[ct], 0, 0, 0);
        }
    }
    #pragma unroll
    for (int ct = 0; ct < 8; ct++) {
        int col = ct * 16 + m;
        float bias = b[col];
        #pragma unroll
        for (int i = 0; i < 4; i++) {
            int r = r0 + q * 4 + i;
            if (r < n_nodes) {
                float v = acc[ct][i] + bias;
                io[(size_t)r * D + col] = v > 0.f ? v : 0.f;
            }
        }
    }
}

extern "C" void kernel_launch(void* const* d_in, const int* in_sizes, int n_in,
                              void* d_out, int out_size, void* d_ws, size_t ws_size,
                              hipStream_t stream) {
    const float* h    = (const float*)d_in[0];
    const int*   esrc = (const int*)d_in[1];
    const int*   edst = (const int*)d_in[2];
    const float* W    = (const float*)d_in[3];
    const float* b    = (const float*)d_in[4];
    float* out = (float*)d_out;
    const int n_nodes = in_sizes[0] / D;
    const int n_edges = in_sizes[1];
    const int NB  = (n_nodes + 1023) / 1024;
    const int NBK = (n_nodes + BKT_SIZE - 1) / BKT_SIZE;

    // ---- main path: bucketed sort + gemm-first + full-row gather ----
    size_t zone_bytes = (size_t)n_edges * 8;                 // pairs
    size_t zb2 = (size_t)n_nodes * D * 2;                    // z (bf16)
    if (zb2 > zone_bytes) zone_bytes = zb2;
    size_t fixed = ((size_t)2 * n_nodes + 2 * NB + NBK + (size_t)n_edges) * 4;
    size_t zone_off = (fixed + 15) & ~(size_t)15;
    size_t need_main = zone_off + zone_bytes;

    if (ws_size >= need_main && NB <= 256 && NBK <= 256) {
        int* cnt        = (int*)d_ws;               // n_nodes (degrees)
        int* offs       = cnt + n_nodes;            // n_nodes (bumped to END by P2)
        int* blocksums  = offs + n_nodes;           // NB
        int* blockoffs  = blocksums + NB;           // NB
        int* bucketCur  = blockoffs + NB;           // NBK
        int* sorted_src = bucketCur + NBK;          // n_edges
        void* zone = (char*)d_ws + zone_off;
        uint2* pairs = (uint2*)zone;
        unsigned short* z = (unsigned short*)zone;  // aliases pairs (sequential use)

        hipMemsetAsync(cnt, 0, (size_t)n_nodes * sizeof(int), stream);
        hist_kernel<<<(n_edges + 255) / 256, 256, 0, stream>>>(edst, cnt, n_edges);
        scanA_kernel<<<NB, 256, 0, stream>>>(cnt, offs, blocksums, n_nodes);
        scanB_kernel<<<1, 256, 0, stream>>>(blocksums, blockoffs, NB);
        scanC_kernel<<<(n_nodes + 255) / 256, 256, 0, stream>>>(
            offs, blockoffs, offs, (int*)nullptr, bucketCur, n_nodes);
        p1_partition_kernel<<<(n_edges + P1_EPB - 1) / P1_EPB, 256, 0, stream>>>(
            esrc, edst, bucketCur, pairs, n_edges);
        p2_place_kernel<<<(n_edges + 255) / 256, 256, 0, stream>>>(
            pairs, offs, sorted_src, n_edges);
        // pairs consumed; zone reused as z
        gemm_z_kernel<<<(n_nodes + 63) / 64, 256, 0, stream>>>(h, W, z, n_nodes);
        gather_row_kernel<<<(n_nodes + 7) / 8, 256, 0, stream>>>(
            z, offs, cnt, sorted_src, b, out, n_nodes);
        return;
    }

    // ---- fallback: round-3 CSR path (fp32 gather + in-place mfma gemm) ----
    size_t csr_ints = (size_t)3 * n_nodes + 2 * NB + (size_t)n_edges;
    size_t needB = csr_ints * sizeof(int);
    if (ws_size >= needB && NB <= 256) {
        int* cnt        = (int*)d_ws;
        int* offs       = cnt + n_nodes;
        int* cursor     = offs + n_nodes;
        int* blocksums  = cursor + n_nodes;
        int* blockoffs  = blocksums + NB;
        int* sorted_src = blockoffs + NB;

        hipMemsetAsync(cnt, 0, (size_t)n_nodes * sizeof(int), stream);
        hist_kernel<<<(n_edges + 255) / 256, 256, 0, stream>>>(edst, cnt, n_edges);
        scanA_kernel<<<NB, 256, 0, stream>>>(cnt, offs, blocksums, n_nodes);
        scanB_kernel<<<1, 256, 0, stream>>>(blocksums, blockoffs, NB);
        scanC_kernel<<<(n_nodes + 255) / 256, 256, 0, stream>>>(
            offs, blockoffs, cnt, cursor, (int*)nullptr, n_nodes);
        place_kernel<<<(n_edges + 255) / 256, 256, 0, stream>>>(
            esrc, edst, cursor, sorted_src, n_edges);
        gather_kernel<<<(n_nodes + 7) / 8, 256, 0, stream>>>(
            h, cnt, cursor, sorted_src, out, n_nodes);
    } else {
        hipMemsetAsync(out, 0, (size_t)n_nodes * D * sizeof(float), stream);
        long long total = (long long)n_edges * 32;
        scatter_kernel<<<(int)((total + 255) / 256), 256, 0, stream>>>(h, esrc, edst, out, n_edges);
    }
    mfma_gemm_relu_kernel<<<(n_nodes + 63) / 64, 256, 0, stream>>>(out, W, b, n_nodes);
}

// Round 6
// 261.873 us; speedup vs baseline: 1.5743x; 1.2761x over previous
//
#include <hip/hip_runtime.h>

#define D 128
#define BKT_SHIFT 9
#define BKT_SIZE 512
#define P1_EPB 4096
#define CNT_EPB 8192
#define SW_LDU 68   // uints per W row in LDS (136 ushorts = 128 + 8 pad)

typedef __attribute__((ext_vector_type(8))) short bf16x8;
typedef __attribute__((ext_vector_type(4))) float f32x4;

__device__ inline unsigned int pack2bf(float a, float b) {
    unsigned int ua = __float_as_uint(a);
    unsigned int ub = __float_as_uint(b);
    ua = (ua + 0x7fffu + ((ua >> 16) & 1u)) >> 16;   // RNE
    ub = (ub + 0x7fffu + ((ub >> 16) & 1u)) >> 16;
    return ua | (ub << 16);
}
__device__ inline unsigned short pack1bf(float a) {
    unsigned int ua = __float_as_uint(a);
    return (unsigned short)((ua + 0x7fffu + ((ua >> 16) & 1u)) >> 16);
}

// ================= bucket-granular CSR build =================

// K1: per-block LDS bucket histogram -> global bucketCnt (NBK<=256)
__global__ __launch_bounds__(256) void bucket_count_kernel(
    const int* __restrict__ edst, int* __restrict__ bucketCnt, int n_edges, int nbk)
{
    __shared__ int hcnt[256];
    const int tid = threadIdx.x;
    hcnt[tid] = 0;
    __syncthreads();
    const int base = blockIdx.x * CNT_EPB;
    const int lim = min(CNT_EPB, n_edges - base);
    for (int k = tid; k < lim; k += 256)
        atomicAdd(&hcnt[edst[base + k] >> BKT_SHIFT], 1);
    __syncthreads();
    if (tid < nbk && hcnt[tid] > 0) atomicAdd(&bucketCnt[tid], hcnt[tid]);
}

// K2: single-block exclusive scan over NBK bucket counts
__global__ __launch_bounds__(256) void bucket_scan_kernel(
    const int* __restrict__ bucketCnt, int* __restrict__ bucketBase,
    int* __restrict__ bucketCur, int nbk)
{
    __shared__ int s[256];
    const int t = threadIdx.x;
    int v = (t < nbk) ? bucketCnt[t] : 0;
    s[t] = v;
    __syncthreads();
    #pragma unroll
    for (int off = 1; off < 256; off <<= 1) {
        int x = (t >= off) ? s[t - off] : 0;
        __syncthreads();
        s[t] += x;
        __syncthreads();
    }
    if (t < nbk) {
        int base = s[t] - v;
        bucketBase[t] = base;
        bucketCur[t] = base;
    }
}

// K3: partition edges into buckets, packed 4B: (src<<9)|local_node
__global__ __launch_bounds__(256) void p1_partition_kernel(
    const int* __restrict__ esrc, const int* __restrict__ edst,
    int* __restrict__ bucketCur, unsigned int* __restrict__ pairs, int n_edges)
{
    __shared__ int hcnt[256];
    __shared__ int hbase[256];
    const int tid = threadIdx.x;
    const int base = blockIdx.x * P1_EPB;
    hcnt[tid] = 0;
    __syncthreads();
    unsigned int pk[16]; int bk[16];
    #pragma unroll
    for (int k = 0; k < 16; k++) {
        int e = base + k * 256 + tid;
        if (e < n_edges) {
            int sv = esrc[e], dv = edst[e];
            bk[k] = dv >> BKT_SHIFT;
            pk[k] = ((unsigned)sv << BKT_SHIFT) | (unsigned)(dv & (BKT_SIZE - 1));
            atomicAdd(&hcnt[bk[k]], 1);
        } else bk[k] = -1;
    }
    __syncthreads();
    int cval = hcnt[tid];
    if (cval > 0) hbase[tid] = atomicAdd(&bucketCur[tid], cval);
    hcnt[tid] = 0;   // reuse as local cursor
    __syncthreads();
    #pragma unroll
    for (int k = 0; k < 16; k++) {
        if (bk[k] >= 0) {
            int loc = atomicAdd(&hcnt[bk[k]], 1);
            pairs[hbase[bk[k]] + loc] = pk[k];
        }
    }
}

// K4: one block per bucket — LDS 512-node histogram + scan -> gstart/gend
// (coalesced) and sorted_src placement inside the bucket's contiguous window.
__global__ __launch_bounds__(256) void p2_sort_kernel(
    const unsigned int* __restrict__ pairs, const int* __restrict__ bucketBase,
    int* __restrict__ sorted_src, int* __restrict__ gstart, int* __restrict__ gend,
    int n_nodes, int n_edges, int nbk)
{
    __shared__ int hist[BKT_SIZE];
    __shared__ int cur[BKT_SIZE];
    __shared__ int sb[256];
    const int tid = threadIdx.x;
    const int bkt = blockIdx.x;
    const int nbase = bkt << BKT_SHIFT;
    const int pstart = bucketBase[bkt];
    const int pend = (bkt == nbk - 1) ? n_edges : bucketBase[bkt + 1];
    hist[tid] = 0; hist[tid + 256] = 0;
    __syncthreads();
    for (int j = pstart + tid; j < pend; j += 256)
        atomicAdd(&hist[pairs[j] & (BKT_SIZE - 1)], 1);
    __syncthreads();
    // exclusive scan of hist[512]: pairwise + 256-wide Hillis-Steele
    int a  = hist[2 * tid];
    int b2 = hist[2 * tid + 1];
    int psum = a + b2;
    sb[tid] = psum;
    __syncthreads();
    #pragma unroll
    for (int off = 1; off < 256; off <<= 1) {
        int x = (tid >= off) ? sb[tid - off] : 0;
        __syncthreads();
        sb[tid] += x;
        __syncthreads();
    }
    int pexcl = sb[tid] - psum;
    cur[2 * tid] = pexcl;
    cur[2 * tid + 1] = pexcl + a;
    __syncthreads();
    // per-node [start,end) — coalesced global writes
    for (int i = tid; i < BKT_SIZE; i += 256) {
        int nd = nbase + i;
        if (nd < n_nodes) {
            int st = pstart + cur[i];
            gstart[nd] = st;
            gend[nd] = st + hist[i];
        }
    }
    __syncthreads();
    // place (writes confined to this bucket's window)
    for (int j = pstart + tid; j < pend; j += 256) {
        unsigned int p = pairs[j];
        int local = p & (BKT_SIZE - 1);
        int pos = pstart + atomicAdd(&cur[local], 1);
        sorted_src[pos] = (int)(p >> BKT_SHIFT);
    }
}

// ================= GEMM first: z = bf16(h @ W^T) =================
__global__ __launch_bounds__(256) void gemm_z_kernel(
    const float* __restrict__ h, const float* __restrict__ W,
    unsigned short* __restrict__ z, int n_nodes)
{
    __shared__ unsigned int sW[128 * SW_LDU];
    const int tid = threadIdx.x;
    for (int i = tid; i < 4096; i += 256) {
        float4 w = ((const float4*)W)[i];
        int row = i >> 5, c4 = i & 31;
        unsigned int* dst = &sW[row * SW_LDU + c4 * 2];
        dst[0] = pack2bf(w.x, w.y);
        dst[1] = pack2bf(w.z, w.w);
    }
    __syncthreads();

    const int wave = tid >> 6;
    const int lane = tid & 63;
    const int m = lane & 15;
    const int q = lane >> 4;
    const int r0 = blockIdx.x * 64 + wave * 16;
    const int arow = r0 + m;
    const bool rvalid = arow < n_nodes;

    bf16x8 afrag[4];
    #pragma unroll
    for (int ks = 0; ks < 4; ks++) {
        float4 x = make_float4(0.f, 0.f, 0.f, 0.f), y = x;
        if (rvalid) {
            const float4* p = (const float4*)(h + (size_t)arow * D + ks * 32 + q * 8);
            x = p[0]; y = p[1];
        }
        union { unsigned int u[4]; bf16x8 v; } cvt;
        cvt.u[0] = pack2bf(x.x, x.y);
        cvt.u[1] = pack2bf(x.z, x.w);
        cvt.u[2] = pack2bf(y.x, y.y);
        cvt.u[3] = pack2bf(y.z, y.w);
        afrag[ks] = cvt.v;
    }

    f32x4 acc[8];
    #pragma unroll
    for (int ct = 0; ct < 8; ct++) acc[ct] = (f32x4){0.f, 0.f, 0.f, 0.f};

    #pragma unroll
    for (int ct = 0; ct < 8; ct++) {
        #pragma unroll
        for (int ks = 0; ks < 4; ks++) {
            const unsigned int* p = &sW[(ct * 16 + m) * SW_LDU + ks * 16 + q * 4];
            union { uint4 u; bf16x8 v; } bu;
            bu.u = *(const uint4*)p;
            acc[ct] = __builtin_amdgcn_mfma_f32_16x16x32_bf16(afrag[ks], bu.v, acc[ct], 0, 0, 0);
        }
    }

    #pragma unroll
    for (int ct = 0; ct < 8; ct++) {
        int col = ct * 16 + m;
        #pragma unroll
        for (int i = 0; i < 4; i++) {
            int r = r0 + q * 4 + i;
            if (r < n_nodes) z[(size_t)r * D + col] = pack1bf(acc[ct][i]);
        }
    }
}

// ================= full-row gather + bias + relu =================
// 16 lanes per node, uint4 (8 bf16) per lane -> 16B loads, more bytes in
// flight per wave. Each edge's 4 cache lines read exactly once.
__global__ __launch_bounds__(256) void gather_row_kernel(
    const unsigned short* __restrict__ z, const int* __restrict__ gstart,
    const int* __restrict__ gend, const int* __restrict__ sorted_src,
    const float* __restrict__ b, float* __restrict__ out, int n_nodes)
{
    const int tid = threadIdx.x;
    const int node = blockIdx.x * 16 + (tid >> 4);
    const int lane = tid & 15;
    if (node >= n_nodes) return;
    int e = gstart[node];
    const int end = gend[node];
    const uint4* __restrict__ z4 = (const uint4*)z;   // 16 uint4 per row
    float acc[8];
    #pragma unroll
    for (int i = 0; i < 8; i++) acc[i] = 0.f;
#define ADDV(v) do { \
    acc[0] += __uint_as_float((v).x << 16); acc[1] += __uint_as_float((v).x & 0xffff0000u); \
    acc[2] += __uint_as_float((v).y << 16); acc[3] += __uint_as_float((v).y & 0xffff0000u); \
    acc[4] += __uint_as_float((v).z << 16); acc[5] += __uint_as_float((v).z & 0xffff0000u); \
    acc[6] += __uint_as_float((v).w << 16); acc[7] += __uint_as_float((v).w & 0xffff0000u); } while (0)
    for (; e + 4 <= end; e += 4) {
        int s0 = sorted_src[e + 0];
        int s1 = sorted_src[e + 1];
        int s2 = sorted_src[e + 2];
        int s3 = sorted_src[e + 3];
        uint4 v0 = z4[(size_t)s0 * 16 + lane];
        uint4 v1 = z4[(size_t)s1 * 16 + lane];
        uint4 v2 = z4[(size_t)s2 * 16 + lane];
        uint4 v3 = z4[(size_t)s3 * 16 + lane];
        ADDV(v0); ADDV(v1); ADDV(v2); ADDV(v3);
    }
    for (; e < end; e++) {
        uint4 v = z4[(size_t)sorted_src[e] * 16 + lane];
        ADDV(v);
    }
#undef ADDV
    float4 b0 = ((const float4*)b)[lane * 2];
    float4 b1 = ((const float4*)b)[lane * 2 + 1];
    float4* o = (float4*)(out + (size_t)node * D + lane * 8);
    o[0] = make_float4(fmaxf(acc[0] + b0.x, 0.f), fmaxf(acc[1] + b0.y, 0.f),
                       fmaxf(acc[2] + b0.z, 0.f), fmaxf(acc[3] + b0.w, 0.f));
    o[1] = make_float4(fmaxf(acc[4] + b1.x, 0.f), fmaxf(acc[5] + b1.y, 0.f),
                       fmaxf(acc[6] + b1.z, 0.f), fmaxf(acc[7] + b1.w, 0.f));
}

// ================= fallback kernels (round-3 path) =================

__global__ __launch_bounds__(256) void hist_kernel(
    const int* __restrict__ edst, int* __restrict__ cnt, int n_edges)
{
    int gid = blockIdx.x * 256 + threadIdx.x;
    if (gid < n_edges) atomicAdd(&cnt[edst[gid]], 1);
}

__global__ __launch_bounds__(256) void scanA_kernel(
    const int* __restrict__ cnt, int* __restrict__ localoff,
    int* __restrict__ blocksums, int n)
{
    __shared__ int s[256];
    const int t = threadIdx.x;
    const int base = blockIdx.x * 1024 + t * 4;
    int v[4]; int sum = 0;
    #pragma unroll
    for (int i = 0; i < 4; i++) {
        int idx = base + i;
        v[i] = (idx < n) ? cnt[idx] : 0;
        sum += v[i];
    }
    s[t] = sum;
    __syncthreads();
    #pragma unroll
    for (int off = 1; off < 256; off <<= 1) {
        int x = (t >= off) ? s[t - off] : 0;
        __syncthreads();
        s[t] += x;
        __syncthreads();
    }
    int excl = s[t] - sum;
    int run = 0;
    #pragma unroll
    for (int i = 0; i < 4; i++) {
        int idx = base + i;
        if (idx < n) localoff[idx] = excl + run;
        run += v[i];
    }
    if (t == 255) blocksums[blockIdx.x] = s[255];
}

__global__ __launch_bounds__(256) void scanB_kernel(
    const int* __restrict__ blocksums, int* __restrict__ blockoffs, int nb)
{
    __shared__ int s[256];
    const int t = threadIdx.x;
    int v = (t < nb) ? blocksums[t] : 0;
    s[t] = v;
    __syncthreads();
    #pragma unroll
    for (int off = 1; off < 256; off <<= 1) {
        int x = (t >= off) ? s[t - off] : 0;
        __syncthreads();
        s[t] += x;
        __syncthreads();
    }
    if (t < nb) blockoffs[t] = s[t] - v;
}

__global__ __launch_bounds__(256) void scanC_kernel(
    const int* __restrict__ localoff, const int* __restrict__ blockoffs,
    int* __restrict__ outoffs, int* __restrict__ cursor, int n)
{
    int gid = blockIdx.x * 256 + threadIdx.x;
    if (gid >= n) return;
    int v = localoff[gid] + blockoffs[blockIdx.x >> 2];
    outoffs[gid] = v;
    if (cursor) cursor[gid] = v;
}

__global__ __launch_bounds__(256) void place_kernel(
    const int* __restrict__ esrc, const int* __restrict__ edst,
    int* __restrict__ cursor, int* __restrict__ sorted_src, int n_edges)
{
    int gid = blockIdx.x * 256 + threadIdx.x;
    if (gid >= n_edges) return;
    int d = edst[gid];
    int pos = atomicAdd(&cursor[d], 1);
    sorted_src[pos] = esrc[gid];
}

__global__ __launch_bounds__(256) void gather_kernel(
    const float* __restrict__ h, const int* __restrict__ offs,
    const int* __restrict__ endp, const int* __restrict__ sorted_src,
    float* __restrict__ out, int n_nodes)
{
    const int tid = threadIdx.x;
    const int node = blockIdx.x * 8 + (tid >> 5);
    const int lane = tid & 31;
    if (node >= n_nodes) return;
    const int start = offs[node];
    const int end = endp[node];
    const float4* __restrict__ h4 = (const float4*)h;
    float4 acc = make_float4(0.f, 0.f, 0.f, 0.f);
    for (int e = start; e < end; e++) {
        float4 a = h4[(size_t)sorted_src[e] * 32 + lane];
        acc.x += a.x; acc.y += a.y; acc.z += a.z; acc.w += a.w;
    }
    ((float4*)out)[(size_t)node * 32 + lane] = acc;
}

__global__ __launch_bounds__(256) void scatter_kernel(
    const float* __restrict__ h, const int* __restrict__ esrc,
    const int* __restrict__ edst, float* __restrict__ out, int n_edges)
{
    int gid = blockIdx.x * 256 + threadIdx.x;
    int e = gid >> 5;
    int l = gid & 31;
    if (e >= n_edges) return;
    int s = esrc[e];
    int d = edst[e];
    float4 v = ((const float4*)(h + (size_t)s * D))[l];
    float* o = out + (size_t)d * D + (size_t)l * 4;
    atomicAdd(o + 0, v.x);
    atomicAdd(o + 1, v.y);
    atomicAdd(o + 2, v.z);
    atomicAdd(o + 3, v.w);
}

__global__ __launch_bounds__(256) void mfma_gemm_relu_kernel(
    float* __restrict__ io, const float* __restrict__ W,
    const float* __restrict__ b, int n_nodes)
{
    __shared__ unsigned int sW[128 * SW_LDU];
    const int tid = threadIdx.x;
    for (int i = tid; i < 4096; i += 256) {
        float4 w = ((const float4*)W)[i];
        int row = i >> 5, c4 = i & 31;
        unsigned int* dst = &sW[row * SW_LDU + c4 * 2];
        dst[0] = pack2bf(w.x, w.y);
        dst[1] = pack2bf(w.z, w.w);
    }
    __syncthreads();
    const int wave = tid >> 6;
    const int lane = tid & 63;
    const int m = lane & 15;
    const int q = lane >> 4;
    const int r0 = blockIdx.x * 64 + wave * 16;
    const int arow = r0 + m;
    const bool rvalid = arow < n_nodes;
    bf16x8 afrag[4];
    #pragma unroll
    for (int ks = 0; ks < 4; ks++) {
        float4 x = make_float4(0.f, 0.f, 0.f, 0.f), y = x;
        if (rvalid) {
            const float4* p = (const float4*)(io + (size_t)arow * D + ks * 32 + q * 8);
            x = p[0]; y = p[1];
        }
        union { unsigned int u[4]; bf16x8 v; } cvt;
        cvt.u[0] = pack2bf(x.x, x.y);
        cvt.u[1] = pack2bf(x.z, x.w);
        cvt.u[2] = pack2bf(y.x, y.y);
        cvt.u[3] = pack2bf(y.z, y.w);
        afrag[ks] = cvt.v;
    }
    f32x4 acc[8];
    #pragma unroll
    for (int ct = 0; ct < 8; ct++) acc[ct] = (f32x4){0.f, 0.f, 0.f, 0.f};
    #pragma unroll
    for (int ct = 0; ct < 8; ct++) {
        #pragma unroll
        for (int ks = 0; ks < 4; ks++) {
            const unsigned int* p = &sW[(ct * 16 + m) * SW_LDU + ks * 16 + q * 4];
            union { uint4 u; bf16x8 v; } bu;
            bu.u = *(const uint4*)p;
            acc[ct] = __builtin_amdgcn_mfma_f32_16x16x32_bf16(afrag[ks], bu.v, acc[ct], 0, 0, 0);
        }
    }
    #pragma unroll
    for (int ct = 0; ct < 8; ct++) {
        int col = ct * 16 + m;
        float bias = b[col];
        #pragma unroll
        for (int i = 0; i < 4; i++) {
            int r = r0 + q * 4 + i;
            if (r < n_nodes) {
                float v = acc[ct][i] + bias;
                io[(size_t)r * D + col] = v > 0.f ? v : 0.f;
            }
        }
    }
}

extern "C" void kernel_launch(void* const* d_in, const int* in_sizes, int n_in,
                              void* d_out, int out_size, void* d_ws, size_t ws_size,
                              hipStream_t stream) {
    const float* h    = (const float*)d_in[0];
    const int*   esrc = (const int*)d_in[1];
    const int*   edst = (const int*)d_in[2];
    const float* W    = (const float*)d_in[3];
    const float* b    = (const float*)d_in[4];
    float* out = (float*)d_out;
    const int n_nodes = in_sizes[0] / D;
    const int n_edges = in_sizes[1];
    const int NB  = (n_nodes + 1023) / 1024;
    const int NBK = (n_nodes + BKT_SIZE - 1) / BKT_SIZE;

    // ---- main path: bucket CSR + gemm-first + full-row gather ----
    size_t zone_bytes = (size_t)n_edges * 4;                 // packed pairs
    size_t zb2 = (size_t)n_nodes * D * 2;                    // z (bf16)
    if (zb2 > zone_bytes) zone_bytes = zb2;
    size_t fixed = ((size_t)2 * n_nodes + 3 * NBK + (size_t)n_edges) * 4;
    size_t zone_off = (fixed + 15) & ~(size_t)15;
    size_t need_main = zone_off + zone_bytes;

    if (ws_size >= need_main && NBK <= 256 && n_nodes <= (1 << 23)) {
        int* gstart     = (int*)d_ws;               // n_nodes
        int* gend       = gstart + n_nodes;         // n_nodes
        int* bucketCnt  = gend + n_nodes;           // NBK
        int* bucketBase = bucketCnt + NBK;          // NBK
        int* bucketCur  = bucketBase + NBK;         // NBK
        int* sorted_src = bucketCur + NBK;          // n_edges
        void* zone = (char*)d_ws + zone_off;
        unsigned int* pairs = (unsigned int*)zone;
        unsigned short* z = (unsigned short*)zone;  // aliases pairs (sequential use)

        hipMemsetAsync(bucketCnt, 0, (size_t)NBK * sizeof(int), stream);
        bucket_count_kernel<<<(n_edges + CNT_EPB - 1) / CNT_EPB, 256, 0, stream>>>(
            edst, bucketCnt, n_edges, NBK);
        bucket_scan_kernel<<<1, 256, 0, stream>>>(bucketCnt, bucketBase, bucketCur, NBK);
        p1_partition_kernel<<<(n_edges + P1_EPB - 1) / P1_EPB, 256, 0, stream>>>(
            esrc, edst, bucketCur, pairs, n_edges);
        p2_sort_kernel<<<NBK, 256, 0, stream>>>(
            pairs, bucketBase, sorted_src, gstart, gend, n_nodes, n_edges, NBK);
        // pairs consumed; zone reused as z
        gemm_z_kernel<<<(n_nodes + 63) / 64, 256, 0, stream>>>(h, W, z, n_nodes);
        gather_row_kernel<<<(n_nodes + 15) / 16, 256, 0, stream>>>(
            z, gstart, gend, sorted_src, b, out, n_nodes);
        return;
    }

    // ---- fallback: round-3 CSR path (fp32 gather + in-place mfma gemm) ----
    size_t csr_ints = (size_t)3 * n_nodes + 2 * NB + (size_t)n_edges;
    size_t needB = csr_ints * sizeof(int);
    if (ws_size >= needB && NB <= 256) {
        int* cnt        = (int*)d_ws;
        int* offs       = cnt + n_nodes;
        int* cursor     = offs + n_nodes;
        int* blocksums  = cursor + n_nodes;
        int* blockoffs  = blocksums + NB;
        int* sorted_src = blockoffs + NB;

        hipMemsetAsync(cnt, 0, (size_t)n_nodes * sizeof(int), stream);
        hist_kernel<<<(n_edges + 255) / 256, 256, 0, stream>>>(edst, cnt, n_edges);
        scanA_kernel<<<NB, 256, 0, stream>>>(cnt, offs, blocksums, n_nodes);
        scanB_kernel<<<1, 256, 0, stream>>>(blocksums, blockoffs, NB);
        scanC_kernel<<<(n_nodes + 255) / 256, 256, 0, stream>>>(
            offs, blockoffs, cnt, cursor, n_nodes);
        place_kernel<<<(n_edges + 255) / 256, 256, 0, stream>>>(
            esrc, edst, cursor, sorted_src, n_edges);
        gather_kernel<<<(n_nodes + 7) / 8, 256, 0, stream>>>(
            h, cnt, cursor, sorted_src, out, n_nodes);
    } else {
        hipMemsetAsync(out, 0, (size_t)n_nodes * D * sizeof(float), stream);
        long long total = (long long)n_edges * 32;
        scatter_kernel<<<(int)((total + 255) / 256), 256, 0, stream>>>(h, esrc, edst, out, n_edges);
    }
    mfma_gemm_relu_kernel<<<(n_nodes + 63) / 64, 256, 0, stream>>>(out, W, b, n_nodes);
}